// Round 11
// baseline (137.312 us; speedup 1.0000x reference)
//
#include <hip/hip_runtime.h>
#include <math.h>

// N_AGENTS=16, RNN_H=64, N_HEADS=4, GAT_D=32, EMB=32, SDIM=128, B=4096 rows

typedef __attribute__((ext_vector_type(8))) short short8;
typedef __attribute__((ext_vector_type(8))) unsigned short ushort8;
typedef __attribute__((ext_vector_type(4))) unsigned short ushort4v;
typedef __attribute__((ext_vector_type(4))) float float4v;
typedef __attribute__((ext_vector_type(4))) _Float16 half4v;

static __device__ inline unsigned short f2bf(float f) {
    unsigned int x;
    __builtin_memcpy(&x, &f, 4);
    unsigned int r = x + 0x7fffu + ((x >> 16) & 1u);   // RNE
    return (unsigned short)(r >> 16);
}

static __device__ inline short8 pack8(float4 f0, float4 f1) {
    ushort8 o;
    o[0] = f2bf(f0.x); o[1] = f2bf(f0.y); o[2] = f2bf(f0.z); o[3] = f2bf(f0.w);
    o[4] = f2bf(f1.x); o[5] = f2bf(f1.y); o[6] = f2bf(f1.z); o[7] = f2bf(f1.w);
    short8 s;
    __builtin_memcpy(&s, &o, 16);
    return s;
}

// ---------------------------------------------------------------------------
// K0: prep + batched small GEMVs.
//  blocks 0..255   : w1s_W -> w1sTf, FRAG-MAJOR bf16 (1KB coalesced frag loads)
//  block 256       : W_gat -> WgTf frag-major (9 tiles incl. fused attention
//                    projections as tile 8)
//  blocks 257..320 : MFMA GEMVs -> b1v, wfv, out = v
// ---------------------------------------------------------------------------
__global__ __launch_bounds__(256) void k0_prep(
    const float* __restrict__ w1s_W,     // [129][4096]
    const float* __restrict__ W_gat,     // [64][128]
    const float* __restrict__ att_a,     // [4][64]
    const float* __restrict__ states,    // [4096][128]
    const float* __restrict__ b1_W, const float* __restrict__ b1_b,
    const float* __restrict__ wf_W, const float* __restrict__ wf_b,
    const float* __restrict__ V1_W, const float* __restrict__ V1_b,
    const float* __restrict__ V2_W, const float* __restrict__ V2_b,
    unsigned short* __restrict__ w1sTf,  // [256 tiles][2048] bf16 frag-major
    unsigned short* __restrict__ WgTf,   // [9 tiles][1024] bf16 frag-major
    float* __restrict__ b1v, float* __restrict__ wfv,
    float* __restrict__ out)             // seeded with v
{
    __shared__ __align__(16) char SMEM[49152];
    const int tid = threadIdx.x, bx = blockIdx.x;

    if (bx < 256) {
        unsigned short* T = (unsigned short*)SMEM;    // [16 cols][136]
        const int c0 = bx * 16;
        const int cc = tid & 15, kr = tid >> 4;
        #pragma unroll
        for (int t = 0; t < 8; ++t) {
            int k = t * 16 + kr;
            T[cc * 136 + k] = f2bf(w1s_W[(size_t)k * 4096 + c0 + cc]);
        }
        __syncthreads();
        const int ks = tid >> 6, q = (tid >> 4) & 3, mm = tid & 15;
        *(ushort8*)&w1sTf[(size_t)bx * 2048 + tid * 8] =
            *(const ushort8*)&T[mm * 136 + ks * 32 + q * 8];
    } else if (bx == 256) {
        unsigned short* T = (unsigned short*)SMEM;    // [128 cols][72]
        #pragma unroll
        for (int t = 0; t < 32; ++t) {
            int i = t * 256 + tid;
            int k = i >> 7, c = i & 127;
            T[c * 72 + k] = f2bf(W_gat[k * 128 + c]);
        }
        __syncthreads();
        #pragma unroll
        for (int t = 0; t < 4; ++t) {
            int i = t * 256 + tid;            // < 1024 ushort8 groups
            int nt = i >> 7, w = i & 127;
            int kh = w >> 6, q = (w >> 4) & 3, mm = w & 15;
            *(ushort8*)&WgTf[nt * 1024 + w * 8] =
                *(const ushort8*)&T[(nt * 16 + mm) * 72 + kh * 32 + q * 8];
        }
        // tile 8: fused attention projections (m = h: src, m = 4+h: dst)
        {
            const int k = tid >> 2, h = tid & 3;
            float ss = 0.f, dd = 0.f;
            #pragma unroll
            for (int d = 0; d < 32; ++d) {
                float wv = W_gat[k * 128 + h * 32 + d];
                ss = fmaf(wv, att_a[h * 64 + d], ss);
                dd = fmaf(wv, att_a[h * 64 + 32 + d], dd);
            }
            const int base = 8192 + (k >> 5) * 512 + ((k >> 3) & 3) * 128 + (k & 7);
            WgTf[base + h * 8]       = f2bf(ss);
            WgTf[base + (4 + h) * 8] = f2bf(dd);
        }
        #pragma unroll
        for (int t = 0; t < 2; ++t) {         // zero cols m = 8..15
            int i = t * 256 + tid;            // < 512
            int kh = i >> 8, q = (i >> 6) & 3, mm = 8 + ((i >> 3) & 7), j = i & 7;
            WgTf[8192 + kh * 512 + q * 128 + mm * 8 + j] = 0;
        }
    } else {
        // ---- MFMA GEMV block: 64 rows, 4 waves x 16 rows ----
        float* WL = (float*)SMEM;             // [3][128][32] = 48KB
        for (int i = tid; i < 12288; i += 256)
            WL[i] = (i < 4096) ? b1_W[i] : (i < 8192 ? wf_W[i - 4096] : V1_W[i - 8192]);
        __syncthreads();

        const int wave = tid >> 6, lane = tid & 63, mm = lane & 15, q = lane >> 4;
        const int b0w = (bx - 257) * 64 + wave * 16;

        short8 a[4];
        #pragma unroll
        for (int ks = 0; ks < 4; ++ks) {
            const float* sp = states + (size_t)(b0w + mm) * 128 + ks * 32 + q * 8;
            a[ks] = pack8(*(const float4*)sp, *(const float4*)(sp + 4));
        }
        float4v accT[6];
        #pragma unroll
        for (int nt = 0; nt < 6; ++nt) accT[nt] = (float4v){0.f, 0.f, 0.f, 0.f};
        #pragma unroll
        for (int nt = 0; nt < 6; ++nt) {
            const int set = nt >> 1, e = (nt & 1) * 16 + mm;
            #pragma unroll
            for (int ks = 0; ks < 4; ++ks) {
                ushort8 bfu;
                #pragma unroll
                for (int j = 0; j < 8; ++j)
                    bfu[j] = f2bf(WL[set * 4096 + (ks * 32 + q * 8 + j) * 32 + e]);
                short8 bf;
                __builtin_memcpy(&bf, &bfu, 16);
                accT[nt] = __builtin_amdgcn_mfma_f32_16x16x32_bf16(a[ks], bf, accT[nt], 0, 0, 0);
            }
        }
        float vsum[4] = {0.f, 0.f, 0.f, 0.f};
        #pragma unroll
        for (int p = 0; p < 2; ++p) {
            const int e = p * 16 + mm;
            const float bb1 = b1_b[e], bwf = wf_b[e], bv1 = V1_b[e], v2 = V2_W[e];
            #pragma unroll
            for (int reg = 0; reg < 4; ++reg) {
                const int row = b0w + q * 4 + reg;
                b1v[(size_t)row * 32 + e] = accT[p][reg] + bb1;
                wfv[(size_t)row * 32 + e] = fabsf(accT[2 + p][reg] + bwf);
                vsum[reg] += fmaxf(accT[4 + p][reg] + bv1, 0.f) * v2;
            }
        }
        #pragma unroll
        for (int reg = 0; reg < 4; ++reg) {
            vsum[reg] += __shfl_xor(vsum[reg], 1);
            vsum[reg] += __shfl_xor(vsum[reg], 2);
            vsum[reg] += __shfl_xor(vsum[reg], 4);
            vsum[reg] += __shfl_xor(vsum[reg], 8);
        }
        if (mm == 0) {
            #pragma unroll
            for (int reg = 0; reg < 4; ++reg)
                out[b0w + q * 4 + reg] = vsum[reg] + V2_b[0];
        }
    }
}

// ---------------------------------------------------------------------------
// K1: GAT, wave = (row, head). Block = 1 row x 4 waves; hidden row staged
// ONCE into LDS (stride-68 pad), barrier, then each wave: 3 B-tiles (its 2
// hp tiles + proj tile) = 6 MFMAs, per-head softmax, 2 f16 MFMA2, g stores.
// 1/4 the serial chain of the 1-wave-per-row version.
// ---------------------------------------------------------------------------
__global__ __launch_bounds__(256) void k1_gat(
    const float* __restrict__ hidden_states,  // [4096*16][64] fp32
    const unsigned short* __restrict__ WgTf,  // [9][1024] bf16 frag-major
    unsigned short* __restrict__ g_bf)        // [B][4][16][32] bf16
{
    const int b = blockIdx.x;
    const int h = threadIdx.x >> 6;           // wave = head
    const int lane = threadIdx.x & 63, m = lane & 15, quad = lane >> 4;
    __shared__ __align__(16) float HS[16 * 68];    // hidden row, 4.25KB
    __shared__ __align__(16) float sc[4 * 320];    // per-wave proj scratch
    float* scr = &sc[h * 320];

    // ---- stage hidden row (1024 floats) coalesced into LDS ----
    {
        const int n = threadIdx.x >> 4, k4 = (threadIdx.x & 15) * 4;
        *(float4*)&HS[n * 68 + k4] =
            *(const float4*)&hidden_states[(size_t)b * 1024 + threadIdx.x * 4];
    }
    __syncthreads();

    // ---- A-frags from LDS (2-way-free bank pattern) ----
    const float* hrow = &HS[m * 68];
    short8 a0 = pack8(*(const float4*)(hrow + quad * 8),
                      *(const float4*)(hrow + quad * 8 + 4));
    short8 a1 = pack8(*(const float4*)(hrow + 32 + quad * 8),
                      *(const float4*)(hrow + 32 + quad * 8 + 4));

    // ---- 3 B-tiles: 2h, 2h+1 (hp) and 8 (proj) ----
    float4v hp0, hp1, pj;
    #pragma unroll
    for (int t = 0; t < 3; ++t) {
        const int nt = (t < 2) ? (2 * h + t) : 8;
        short8 bf0 = *(const short8*)&WgTf[nt * 1024 + lane * 8];
        short8 bf1 = *(const short8*)&WgTf[nt * 1024 + 512 + lane * 8];
        float4v z = (float4v){0.f, 0.f, 0.f, 0.f};
        z = __builtin_amdgcn_mfma_f32_16x16x32_bf16(a0, bf0, z, 0, 0, 0);
        z = __builtin_amdgcn_mfma_f32_16x16x32_bf16(a1, bf1, z, 0, 0, 0);
        if (t == 0) hp0 = z; else if (t == 1) hp1 = z; else pj = z;
    }

    // stash proj tile transposed: scr[col*20 + row]  (cols 0..7 used)
    {
        float4 pr = {pj[0], pj[1], pj[2], pj[3]};
        *(float4*)&scr[m * 20 + quad * 4] = pr;
    }

    // ---- softmax for head h ----
    const float src_m = scr[h * 20 + m];                        // src[i=m]
    float4 pdv = *(const float4*)&scr[(4 + h) * 20 + quad * 4]; // dst[j]
    float pd[4] = {pdv.x, pdv.y, pdv.z, pdv.w};

    float e_[4];
    #pragma unroll
    for (int jj = 0; jj < 4; ++jj) {
        float x = src_m + pd[jj];
        e_[jj] = fmaxf(x, 0.2f * x);       // leaky_relu(0.2)
    }
    float mx = fmaxf(fmaxf(e_[0], e_[1]), fmaxf(e_[2], e_[3]));
    mx = fmaxf(mx, __shfl_xor(mx, 16));
    mx = fmaxf(mx, __shfl_xor(mx, 32));
    float p_[4], ssum = 0.f;
    #pragma unroll
    for (int jj = 0; jj < 4; ++jj) { p_[jj] = __expf(e_[jj] - mx); ssum += p_[jj]; }
    ssum += __shfl_xor(ssum, 16);
    ssum += __shfl_xor(ssum, 32);
    const float inv = __builtin_amdgcn_rcpf(ssum);

    half4v bfrag;   // B[k=j=quad*4+jj][n=i=m] = attn[i][j]
    #pragma unroll
    for (int jj = 0; jj < 4; ++jj) bfrag[jj] = (_Float16)(p_[jj] * inv);

    // ---- MFMA2: g = attn-weighted hp ----
    #pragma unroll
    for (int p = 0; p < 2; ++p) {
        float4v ct = (p == 0) ? hp0 : hp1;  // A[m=d'][k=j=quad*4+t]
        half4v afrag;
        #pragma unroll
        for (int t = 0; t < 4; ++t) afrag[t] = (_Float16)ct[t];
        float4v z = (float4v){0.f, 0.f, 0.f, 0.f};
        z = __builtin_amdgcn_mfma_f32_16x16x16f16(afrag, bfrag, z, 0, 0, 0);
        ushort4v o;
        #pragma unroll
        for (int t = 0; t < 4; ++t) {
            float x = z[t];
            float ex = __expf(x) - 1.f;    // elu
            x = (x > 0.f) ? x : ex;
            o[t] = f2bf(x);
        }
        *(ushort4v*)&g_bf[((size_t)b * 4 + h) * 512 + m * 32 + p * 16 + quad * 4] = o;
    }
}

// ---------------------------------------------------------------------------
// K2_mix v2: occupancy-first fused GEMM + contraction + epilogue.
// Block = (16-row strip, e-group of 8 e's); grid (256,4) x 4 waves.
// Per h: phase1 GEMM 16 rows x 256 cols -> bf16 LDS (double-buffered,
// conflict-free b128 phase-2 reads); gf prefetch; ONE barrier; phase2:
// 4 rows/wave, direct-bf16 A-frag MFMA vs g, deferred-abs h-accumulation.
// Epilogue: qs, n-reduce, b1+elu+wf, atomic out.
// ---------------------------------------------------------------------------
__global__ __launch_bounds__(256) void k2_mix(
    const float* __restrict__ states,           // [4096][128] fp32
    const unsigned short* __restrict__ w1sTf,   // [256 tiles][2048] frag-major
    const unsigned short* __restrict__ g_bf,    // [4096][4][16][32]
    const float* __restrict__ agent_qs,         // [4096][16]
    const float* __restrict__ uncertainty,      // [4096]
    const float* __restrict__ w1s_W,            // row 128 used
    const float* __restrict__ w1s_b,
    const float* __restrict__ b1v, const float* __restrict__ wfv,
    float* __restrict__ out)                    // pre-seeded with v
{
    const int r0 = blockIdx.x * 16;
    const int eg = blockIdx.y;
    const int wave = threadIdx.x >> 6;
    const int lane = threadIdx.x & 63, m = lane & 15, quad = lane >> 4;
    __shared__ __align__(16) unsigned short Wt[2][16 * 328];   // 21KB dbuf

    short8 a[4];
    #pragma unroll
    for (int ks = 0; ks < 4; ++ks) {
        const float* sp = states + (size_t)(r0 + m) * 128 + ks * 32 + quad * 8;
        a[ks] = pack8(*(const float4*)sp, *(const float4*)(sp + 4));
    }
    float us[4];
    #pragma unroll
    for (int reg = 0; reg < 4; ++reg)
        us[reg] = uncertainty[r0 + quad * 4 + reg];
    float qs_r[4];
    #pragma unroll
    for (int rr = 0; rr < 4; ++rr)
        qs_r[rr] = agent_qs[(r0 + wave * 4 + rr) * 16 + m];

    const float* w128 = w1s_W + (size_t)128 * 4096;
    float Sacc[4][4] = {};

    #pragma unroll
    for (int h = 0; h < 4; ++h) {
        unsigned short* buf = &Wt[h & 1][0];

        // ---- Phase 1: wave w -> col-tiles w*4..+4 (16 MFMA) ----
        #pragma unroll
        for (int t = 0; t < 4; ++t) {
            const int ctl = wave * 4 + t;                // local col-tile
            const int ct = h * 64 + eg * 16 + ctl;       // global col-tile
            const int c_loc = ctl * 16 + m;
            const int cg = h * 1024 + eg * 256 + c_loc;
            const float wfix = w128[cg], bias = w1s_b[cg];
            float4v acc = (float4v){0.f, 0.f, 0.f, 0.f};
            #pragma unroll
            for (int ks = 0; ks < 4; ++ks) {
                short8 bfr = *(const short8*)&w1sTf[(size_t)ct * 2048 + ks * 512 + lane * 8];
                acc = __builtin_amdgcn_mfma_f32_16x16x32_bf16(a[ks], bfr, acc, 0, 0, 0);
            }
            const int el = c_loc >> 5, d = c_loc & 31;
            #pragma unroll
            for (int reg = 0; reg < 4; ++reg)
                buf[(quad * 4 + reg) * 328 + el * 40 + d] =
                    f2bf(acc[reg] + us[reg] * wfix + bias);
        }

        // prefetch g frags (global, independent of LDS) before the barrier
        short8 gf[4];
        #pragma unroll
        for (int rr = 0; rr < 4; ++rr)
            gf[rr] = *(const short8*)&g_bf[((size_t)(r0 + wave * 4 + rr) * 4 + h) * 512 + m * 32 + quad * 8];

        __syncthreads();

        // ---- Phase 2: wave w -> rows w*4..+4; Sacc += |z| ----
        #pragma unroll
        for (int rr = 0; rr < 4; ++rr) {
            const int r = wave * 4 + rr;
            short8 af = *(const short8*)&buf[r * 328 + (m & 7) * 40 + quad * 8];
            float4v z = (float4v){0.f, 0.f, 0.f, 0.f};
            z = __builtin_amdgcn_mfma_f32_16x16x32_bf16(af, gf[rr], z, 0, 0, 0);
            #pragma unroll
            for (int reg = 0; reg < 4; ++reg)
                Sacc[rr][reg] += fabsf(z[reg]);
        }
        // next h writes the other buffer; reuse separated by next barrier
    }

    // ---- Epilogue: qs, n-reduce, b1+elu+wf, e-sum, atomic into out ----
    #pragma unroll
    for (int rr = 0; rr < 4; ++rr) {
        const int r = r0 + wave * 4 + rr;
        float sn[4];
        #pragma unroll
        for (int reg = 0; reg < 4; ++reg) sn[reg] = Sacc[rr][reg] * qs_r[rr];
        #pragma unroll
        for (int mask = 1; mask <= 8; mask <<= 1) {
            #pragma unroll
            for (int reg = 0; reg < 4; ++reg) sn[reg] += __shfl_xor(sn[reg], mask);
        }
        const float* bb = &b1v[(size_t)r * 32 + eg * 8 + (quad & 1) * 4];
        const float* ww = &wfv[(size_t)r * 32 + eg * 8 + (quad & 1) * 4];
        float4 b4 = *(const float4*)bb;
        float4 w4 = *(const float4*)ww;
        float bq[4] = {b4.x, b4.y, b4.z, b4.w};
        float wq[4] = {w4.x, w4.y, w4.z, w4.w};
        float local = 0.f;
        #pragma unroll
        for (int reg = 0; reg < 4; ++reg) {
            float hid = 0.25f * sn[reg] + bq[reg];
            hid = (hid > 0.f) ? hid : expm1f(hid);
            local = fmaf(hid, wq[reg], local);
        }
        local += __shfl_xor(local, 16);   // quad0+quad1 (2/3 duplicate)
        if (lane == 0) atomicAdd(&out[r], local);
    }
}

// ---------------------------------------------------------------------------
extern "C" void kernel_launch(void* const* d_in, const int* in_sizes, int n_in,
                              void* d_out, int out_size, void* d_ws, size_t ws_size,
                              hipStream_t stream)
{
    const float* agent_qs      = (const float*)d_in[0];
    const float* states        = (const float*)d_in[1];
    const float* hidden_states = (const float*)d_in[2];
    const float* uncertainty   = (const float*)d_in[3];
    const float* W_gat         = (const float*)d_in[4];
    const float* att_a         = (const float*)d_in[5];
    const float* w1s_W         = (const float*)d_in[6];
    const float* w1s_b         = (const float*)d_in[7];
    const float* b1_W          = (const float*)d_in[8];
    const float* b1_b          = (const float*)d_in[9];
    const float* wf_W          = (const float*)d_in[10];
    const float* wf_b          = (const float*)d_in[11];
    const float* V1_W          = (const float*)d_in[12];
    const float* V1_b          = (const float*)d_in[13];
    const float* V2_W          = (const float*)d_in[14];
    const float* V2_b          = (const float*)d_in[15];

    char* w = (char*)d_ws;
    unsigned short* w1sTf   = (unsigned short*)w;  w += (size_t)524288 * 2;
    unsigned short* WgTf    = (unsigned short*)w;  w += (size_t)9216 * 2;
    unsigned short* g_bf    = (unsigned short*)w;  w += (size_t)8388608 * 2;
    float* b1v              = (float*)w;           w += (size_t)131072 * 4;
    float* wfv              = (float*)w;           w += (size_t)131072 * 4;
    float* out              = (float*)d_out;

    k0_prep<<<321, 256, 0, stream>>>(w1s_W, W_gat, att_a, states,
                                     b1_W, b1_b, wf_W, wf_b, V1_W, V1_b,
                                     V2_W, V2_b, w1sTf, WgTf, b1v, wfv, out);

    k1_gat<<<4096, 256, 0, stream>>>(hidden_states, WgTf, g_bf);

    dim3 gmix(256, 4);
    k2_mix<<<gmix, 256, 0, stream>>>(states, w1sTf, g_bf, agent_qs, uncertainty,
                                     w1s_W, w1s_b, b1v, wfv, out);
}